// Round 15
// baseline (38406.064 us; speedup 1.0000x reference)
//
#include <hip/hip_runtime.h>
#include <math.h>

// Problem dims
#define TSTEPS 512
#define BSZ    64
#define INDIM  256
#define HDIM   1024
#define G4     4096
#define NX     5120   // xg cols: 4096 gate + 1024 proj
#define LN_EPS 1e-5f

#define NBLK   256
#define NTHR   1024
#define CHUNK  8
#define CROWS  (CHUNK * BSZ)
#define NCHUNK (TSTEPS / CHUNK)
#define HRING  16            // h ring slots; acquire fence every 16 steps
#define HSLOT  65536         // u16 per slot (64 x 1024)

// LDS: 2 W1 strips, HI ONLY (lo streamed from L2). [2 strips][16 cols][2054]
// stride 2054 u16 == 3 mod 32 dwords: conflict-free (R8-verified).
#define LDS_LDK    2054
#define LDS_W_BYTES (2 * 16 * LDS_LDK * 2)          // 131,456
#define LDS_STG_OFF LDS_W_BYTES                     // u16 stg_h[2048] = 4 KB
#define LDS_RED_OFF (LDS_W_BYTES + 4096)            // float red[16] (+pad)
#define LDS_GST_OFF (LDS_RED_OFF + 256)             // float stg_g[16][256] = 16 KB
#define LDS_BYTES   (LDS_GST_OFF + 16384)           // 152,192 < 160 KB

typedef short          s8v __attribute__((ext_vector_type(8)));
typedef float          f4v __attribute__((ext_vector_type(4)));
typedef unsigned short u16;

#define MFMA __builtin_amdgcn_mfma_f32_16x16x32_bf16

__device__ __forceinline__ u16 f2bf(float f) {
    unsigned u = __float_as_uint(f);
    u += 0x7FFFu + ((u >> 16) & 1u);
    return (u16)(u >> 16);
}
__device__ __forceinline__ float bf2f(u16 h) {
    return __uint_as_float(((unsigned)h) << 16);
}
__device__ __forceinline__ float sigm(float x) { return 1.f / (1.f + expf(-x)); }

// ---- sc1 (L2-bypass, always-fresh) accessors for read-once mutable data ----
__device__ __forceinline__ float aldf(const float* p) {
    unsigned v = __hip_atomic_load((unsigned*)p, __ATOMIC_RELAXED,
                                   __HIP_MEMORY_SCOPE_AGENT);
    return __uint_as_float(v);
}
__device__ __forceinline__ void ast16B(u16* p, s8v v) {
    asm volatile("global_store_dwordx4 %0, %1, off sc1"
                 :: "v"(p), "v"(v) : "memory");
}
__device__ __forceinline__ void ast16Bf(float* p, f4v v) {
    asm volatile("global_store_dwordx4 %0, %1, off sc1"
                 :: "v"(p), "v"(v) : "memory");
}

// ---- GEMM C-write: per-wave LDS stage -> one contiguous 16B/lane sc1 store.
__device__ __forceinline__ void store_c_16B(float* stgw, int lane, f4v acc,
                                            float* dst, int ld)
{
    const int row = lane & 15, kg = lane >> 4;
#pragma unroll
    for (int r = 0; r < 4; ++r)
        stgw[(kg * 4 + r) * 16 + row] = acc[r];
    f4v v = *(f4v*)(stgw + lane * 4);
    ast16Bf(dst + (lane >> 2) * ld + (lane & 3) * 4, v);
}

// ---------------- tree grid barrier (R13 form) -----------------------------
#define GSTRIDE 512
__device__ __forceinline__ void grid_barrier(int* bar, int nbar, bool fence)
{
    asm volatile("s_waitcnt vmcnt(0)" ::: "memory");
    __syncthreads();
    if (threadIdx.x == 0) {
        const int g = blockIdx.x & 15;
        int* gctr = bar + g * GSTRIDE;
        int* ggo  = gctr + 32;
        int* root = bar + 16 * GSTRIDE;
        int v = __hip_atomic_fetch_add(gctr, 1, __ATOMIC_RELAXED,
                                       __HIP_MEMORY_SCOPE_AGENT);
        if (v == nbar * 16 - 1) {
            int rv = __hip_atomic_fetch_add(root, 1, __ATOMIC_RELAXED,
                                            __HIP_MEMORY_SCOPE_AGENT);
            if (rv == nbar * 16 - 1) {
#pragma unroll
                for (int g2 = 0; g2 < 16; ++g2)
                    __hip_atomic_store(bar + g2 * GSTRIDE + 32, nbar,
                                       __ATOMIC_RELAXED, __HIP_MEMORY_SCOPE_AGENT);
            }
        }
        while (__hip_atomic_load(ggo, __ATOMIC_RELAXED,
                                 __HIP_MEMORY_SCOPE_AGENT) < nbar) {}
        if (fence)
            __builtin_amdgcn_fence(__ATOMIC_ACQUIRE, "agent");  // inv L1/L2
        asm volatile("" ::: "memory");
    }
    __syncthreads();
}

// ---------------- taskA: gates0 h-part, K-split 2 (16 iters/wave) ----------
// task t < 2048: ks=t&1, rt=(t>>1)&3, ct=t>>3
__device__ __forceinline__ void taskA(int t, int lane, float* stgw,
    const u16* __restrict__ h0hi_s, const u16* __restrict__ h0lo_s,
    const u16* __restrict__ Whthi, const u16* __restrict__ Whtlo,
    float* __restrict__ parts0)
{
    const int ks = t & 1, rt = (t >> 1) & 3, ct = t >> 3;
    const int row = lane & 15, kg = lane >> 4;
    const int m = rt * 16 + row;
    const u16* wh = Whthi + (size_t)(ct * 16 + row) * HDIM + ks * 512 + kg * 8;
    const u16* wl = Whtlo + (size_t)(ct * 16 + row) * HDIM + ks * 512 + kg * 8;
    const u16* ah = h0hi_s + (size_t)m * HDIM + ks * 512 + kg * 8;
    const u16* al = h0lo_s + (size_t)m * HDIM + ks * 512 + kg * 8;
    f4v acc = {0.f, 0.f, 0.f, 0.f};
    s8v Ah = *(const s8v*)(ah);
    s8v Al = *(const s8v*)(al);
    s8v Bh = *(const s8v*)(wh);
    s8v Bl = *(const s8v*)(wl);
#pragma unroll
    for (int i = 0; i < 16; ++i) {
        s8v nAh, nAl, nBh, nBl;
        if (i + 1 < 16) {
            const int kn = (i + 1) * 32;
            nAh = *(const s8v*)(ah + kn);
            nAl = *(const s8v*)(al + kn);
            nBh = *(const s8v*)(wh + kn);
            nBl = *(const s8v*)(wl + kn);
        }
        acc = MFMA(Ah, Bh, acc, 0, 0, 0);
        acc = MFMA(Ah, Bl, acc, 0, 0, 0);
        acc = MFMA(Al, Bh, acc, 0, 0, 0);
        Ah = nAh; Al = nAl; Bh = nBh; Bl = nBl;
    }
    store_c_16B(stgw, lane, acc,
                parts0 + (size_t)ks * BSZ * G4 + (size_t)(rt * 16) * G4 + ct * 16,
                G4);
}

// ---------------- taskX: xg chunk GEMM, one 16x16 tile, K=256 --------------
__device__ __forceinline__ void taskX(int task, int c, int lane, float* stgw,
    const u16* __restrict__ xhi, const u16* __restrict__ xlo,
    const u16* __restrict__ Wxthi, const u16* __restrict__ Wxtlo,
    float* __restrict__ xgbuf)
{
    const int mt = task & 31, ct = task >> 5;
    const int row = lane & 15, kg = lane >> 4;
    const int mr = mt * 16 + row;
    const u16* ah = xhi + ((size_t)c * CROWS + mr) * INDIM + kg * 8;
    const u16* al = xlo + ((size_t)c * CROWS + mr) * INDIM + kg * 8;
    const u16* wh = Wxthi + (size_t)(ct * 16 + row) * INDIM + kg * 8;
    const u16* wl = Wxtlo + (size_t)(ct * 16 + row) * INDIM + kg * 8;
    f4v acc = {0.f, 0.f, 0.f, 0.f};
    s8v Ah = *(const s8v*)(ah);
    s8v Al = *(const s8v*)(al);
    s8v Bh = *(const s8v*)(wh);
    s8v Bl = *(const s8v*)(wl);
#pragma unroll
    for (int i = 0; i < 8; ++i) {
        s8v nAh, nAl, nBh, nBl;
        if (i + 1 < 8) {
            const int kn = (i + 1) * 32;
            nAh = *(const s8v*)(ah + kn);
            nAl = *(const s8v*)(al + kn);
            nBh = *(const s8v*)(wh + kn);
            nBl = *(const s8v*)(wl + kn);
        }
        acc = MFMA(Ah, Bh, acc, 0, 0, 0);
        acc = MFMA(Ah, Bl, acc, 0, 0, 0);
        acc = MFMA(Al, Bh, acc, 0, 0, 0);
        Ah = nAh; Al = nAl; Bh = nBh; Bl = nBl;
    }
    store_c_16B(stgw, lane, acc,
                xgbuf + (size_t)(mt * 16) * NX + ct * 16, NX);
}

// ---------------- taskC: GEMM1. Blocks 64..191 host 2 col-tiles each. ------
// wv: s=wv>>3 (strip), hs=(wv>>2)&1 (K half), rt=wv&3. ct=2*(blk-64)+s.
// B-hi from LDS strip, B-lo streamed from L2 (per-XCD footprint 2MB).
__device__ __forceinline__ void taskC(int blk, int wv, int lane, float* stgw,
    const u16* __restrict__ shW, const u16* __restrict__ W1tlo,
    const u16* __restrict__ h0hi_s, const u16* __restrict__ h0lo_s,
    const u16* __restrict__ h1hi_s, const u16* __restrict__ h1lo_s,
    float* __restrict__ parts1)
{
    const int s = wv >> 3, hs = (wv >> 2) & 1, rt = wv & 3;
    const int ct = 2 * (blk - 64) + s;
    const int row = lane & 15, kg = lane >> 4;
    const int m = rt * 16 + row;
    const u16* ah0 = (hs ? h1hi_s : h0hi_s) + (size_t)m * HDIM + kg * 8;
    const u16* al0 = (hs ? h1lo_s : h0lo_s) + (size_t)m * HDIM + kg * 8;
    const u16* sh  = shW + (size_t)(s * 16 + row) * LDS_LDK + hs * 1024 + kg * 8;
    const u16* wl  = W1tlo + (size_t)(ct * 16 + row) * 2048 + hs * 1024 + kg * 8;
    f4v acc = {0.f, 0.f, 0.f, 0.f};
    s8v Ah = *(const s8v*)(ah0);
    s8v Al = *(const s8v*)(al0);
    s8v Bl = *(const s8v*)(wl);
#pragma unroll
    for (int i = 0; i < 32; ++i) {
        s8v nAh, nAl, nBl;
        if (i + 1 < 32) {
            const int kn = (i + 1) * 32;
            nAh = *(const s8v*)(ah0 + kn);
            nAl = *(const s8v*)(al0 + kn);
            nBl = *(const s8v*)(wl + kn);
        }
        s8v Bh = *(const s8v*)(sh + i * 32);
        acc = MFMA(Ah, Bh, acc, 0, 0, 0);
        acc = MFMA(Ah, Bl, acc, 0, 0, 0);
        acc = MFMA(Al, Bh, acc, 0, 0, 0);
        Ah = nAh; Al = nAl; Bl = nBl;
    }
    store_c_16B(stgw, lane, acc,
                parts1 + (size_t)hs * BSZ * G4 + (size_t)(rt * 16) * G4 + ct * 16,
                G4);
}

// ---------------- block reduction + LN helpers -----------------------------
__device__ __forceinline__ float2 blk_sum2(float s, float q, float* red, int tid)
{
#pragma unroll
    for (int off = 32; off; off >>= 1) {
        s += __shfl_down(s, off);
        q += __shfl_down(q, off);
    }
    if ((tid & 63) == 0) { red[(tid >> 6) * 2] = s; red[(tid >> 6) * 2 + 1] = q; }
    __syncthreads();
    float ts = 0.f, tq = 0.f;
#pragma unroll
    for (int i = 0; i < 16; ++i) { ts += red[2 * i]; tq += red[2 * i + 1]; }
    __syncthreads();
    return make_float2(ts, tq);
}

__device__ __forceinline__ float lnorm(float v, float2 sq, float g, float b)
{
    float mean = sq.x * (1.f / 1024.f);
    float var  = sq.y * (1.f / 1024.f) - mean * mean;
    return (v - mean) * rsqrtf(var + LN_EPS) * g + b;
}

// stage h (hi,lo per-thread u16) through LDS -> 16B sc1 stores
__device__ __forceinline__ void store_h_16B(u16* stg, int tid,
                                            u16 hi, u16 lo,
                                            u16* dhi, u16* dlo, int base)
{
    stg[tid] = hi;
    stg[1024 + tid] = lo;
    __syncthreads();
    if (tid < 256) {
        const u16* src = stg + (tid >> 7) * 1024 + (tid & 127) * 8;
        s8v v = *(const s8v*)src;
        u16* dst = ((tid >> 7) == 0 ? dhi : dlo) + base + (tid & 127) * 8;
        ast16B(dst, v);
    }
    __syncthreads();
}

// =====================================================================
__global__ __launch_bounds__(NTHR, 4) void persistent(
    const u16* __restrict__ xhi,  const u16* __restrict__ xlo,
    const u16* __restrict__ Whthi, const u16* __restrict__ Whtlo,
    const u16* __restrict__ Wxthi, const u16* __restrict__ Wxtlo,
    const u16* __restrict__ W1thi, const u16* __restrict__ W1tlo,
    const float* __restrict__ b0, const float* __restrict__ b1,
    const float* __restrict__ lncg, const float* __restrict__ lncb,
    const float* __restrict__ lnhg, const float* __restrict__ lnhb,
    const float* __restrict__ lnog, const float* __restrict__ lnob,
    float* __restrict__ xg,                        // [2][512][5120]  (sc1)
    float* __restrict__ parts0,                    // [2][64][4096]   (sc1)
    float* __restrict__ parts1,                    // [2][64][4096]   (sc1)
    u16* __restrict__ h0hi, u16* __restrict__ h0lo,// [HRING][64][1024]
    u16* __restrict__ h1hi, u16* __restrict__ h1lo,// [HRING][64][1024]
    float* __restrict__ out, int* bar)
{
    extern __shared__ char smem[];
    u16*   shW   = (u16*)smem;
    u16*   stg   = (u16*)(smem + LDS_STG_OFF);
    float* red   = (float*)(smem + LDS_RED_OFF);
    float* stg_g = (float*)(smem + LDS_GST_OFF);

    const int blk  = blockIdx.x;
    const int tid  = threadIdx.x;
    const int wv   = tid >> 6;
    const int lane = tid & 63;
    float* stgw = stg_g + wv * 256;
    int nbar = 0;

    // recurrent per-thread state:
    //   blocks 0..63: c0,h0 of batch row blk; blocks 64..127: c1,h1 of row blk-64
    float c0reg = 0.f, h0reg = 0.f, c1reg = 0.f, h1reg = 0.f;

    // ---- prologue: LDS W1-HI strips (blocks 64..191 host tiles 2(blk-64)+s) --
    if (blk >= 64 && blk < 192) {
        const int s = wv >> 3;
        const int ct = 2 * (blk - 64) + s;
        for (int cc = wv & 7; cc < 16; cc += 8) {
            const size_t gcol = (size_t)(ct * 16 + cc) * 2048;
            for (int j = lane * 8; j < 2048; j += 512)
                *(s8v*)(shW + (size_t)(s * 16 + cc) * LDS_LDK + j) =
                    *(const s8v*)(W1thi + gcol + j);
        }
    }
    grid_barrier(bar, ++nbar, false);

    // ---- prologue: xg chunk 0 (all blocks; 10240 tasks / 4096 waves) ----
    {
        const int g = blk * 16 + wv;
        for (int task = g; task < 10240; task += 4096)
            taskX(task, 0, lane, stgw, xhi, xlo, Wxthi, Wxtlo, xg);
    }
    grid_barrier(bar, ++nbar, false);
    // parts0 zeroed host-side (h0(-1)=0); h rings zeroed host-side.

    // Schedule (2 barriers/iter, balanced):
    //  Phase A(u): cell0(u) [blk 0-63] || taskC(u-1) [blk 64-191] || taskX [192-255]
    //  Phase B(u): cell1(u-1) [blk 64-127] || taskA(u+1) [blk 0-63,128-255]
    for (int u = 0; u <= TSTEPS; ++u) {
        const int s0  = u & (HRING - 1);            // h0(u) slot
        const int sA0 = (u - 1) & (HRING - 1);      // h0(u-1) / h1(u-1) slot
        const int sA1 = (u - 2) & (HRING - 1);      // h1(u-2) slot
        const bool fence = ((u & 15) == 15);

        // ================= phase A =================
        if (blk < 64) {
            if (u < TSTEPS) {
                // ---- cell0(u): row b = blk ----
                const int b = blk, n = tid;
                const float* XG = xg + (size_t)((u >> 3) & 1) * CROWS * NX
                                     + (size_t)((u & 7) * BSZ + b) * NX;
                const float* P0 = parts0 + (size_t)b * G4;
                const float* P1 = parts0 + (size_t)(BSZ + b) * G4;
                float gi = aldf(&XG[n])        + aldf(&P0[n])        + aldf(&P1[n])        + b0[n];
                float gf = aldf(&XG[1024 + n]) + aldf(&P0[1024 + n]) + aldf(&P1[1024 + n]) + b0[1024 + n];
                float gg = aldf(&XG[2048 + n]) + aldf(&P0[2048 + n]) + aldf(&P1[2048 + n]) + b0[2048 + n];
                float go = aldf(&XG[3072 + n]) + aldf(&P0[3072 + n]) + aldf(&P1[3072 + n]) + b0[3072 + n];
                float xp = aldf(&XG[4096 + n]);
                float cv = sigm(gf) * c0reg + expf(gi) * tanhf(gg);
                float2 r = blk_sum2(cv, cv * cv, red, tid);
                float cl = lnorm(cv, r, lncg[n], lncb[n]);
                c0reg = cl;
                float hv = sigm(go) * tanhf(cl);
                r = blk_sum2(hv, hv * hv, red, tid);
                float hl = lnorm(hv, r, lnhg[n], lnhb[n]) + xp;
                r = blk_sum2(hl, hl * hl, red, tid);
                float hn = lnorm(hl, r, lnog[n], lnob[n]);
                h0reg = hn;
                u16 hi = f2bf(hn);
                store_h_16B(stg, tid, hi, f2bf(hn - bf2f(hi)),
                            h0hi + (size_t)s0 * HSLOT, h0lo + (size_t)s0 * HSLOT,
                            blk * HDIM);
            }
        } else if (blk < 192) {
            if (u >= 1)
                taskC(blk, wv, lane, stgw, shW, W1tlo,
                      h0hi + (size_t)sA0 * HSLOT, h0lo + (size_t)sA0 * HSLOT,
                      h1hi + (size_t)sA1 * HSLOT, h1lo + (size_t)sA1 * HSLOT,
                      parts1);
        } else {
            const int c = (u >> 3) + 1;
            if (c < NCHUNK && u < TSTEPS) {
                float* xgbuf = xg + (size_t)(c & 1) * CROWS * NX;
                const int widx = (blk - 192) * 16 + wv;       // 0..1023
                taskX((u & 7) * 1280 + widx, c, lane, stgw,
                      xhi, xlo, Wxthi, Wxtlo, xgbuf);
                if (widx + 1024 < 1280)
                    taskX((u & 7) * 1280 + widx + 1024, c, lane, stgw,
                          xhi, xlo, Wxthi, Wxtlo, xgbuf);
            }
        }
        grid_barrier(bar, ++nbar, false);

        // ================= phase B =================
        if (blk >= 64 && blk < 128) {
            if (u >= 1) {
                // ---- cell1(u-1): row b = blk-64 ----
                const int b = blk - 64, n = tid;
                const float* P0 = parts1 + (size_t)b * G4;
                const float* P1 = parts1 + (size_t)(BSZ + b) * G4;
                float gi = aldf(&P0[n])        + aldf(&P1[n])        + b1[n];
                float gf = aldf(&P0[1024 + n]) + aldf(&P1[1024 + n]) + b1[1024 + n];
                float gg = aldf(&P0[2048 + n]) + aldf(&P1[2048 + n]) + b1[2048 + n];
                float go = aldf(&P0[3072 + n]) + aldf(&P1[3072 + n]) + b1[3072 + n];
                float cv = sigm(gf) * c1reg + expf(gi) * tanhf(gg);
                float2 r = blk_sum2(cv, cv * cv, red, tid);
                float cl = lnorm(cv, r, lncg[HDIM + n], lncb[HDIM + n]);
                c1reg = cl;
                float hv = sigm(go) * tanhf(cl);
                r = blk_sum2(hv, hv * hv, red, tid);
                // residual h0(u-1): cached ring read (L2-warm from taskC)
                float h0v = bf2f(h0hi[(size_t)sA0 * HSLOT + b * HDIM + n])
                          + bf2f(h0lo[(size_t)sA0 * HSLOT + b * HDIM + n]);
                float hl = lnorm(hv, r, lnhg[HDIM + n], lnhb[HDIM + n]) + h0v;
                r = blk_sum2(hl, hl * hl, red, tid);
                float hn = lnorm(hl, r, lnog[HDIM + n], lnob[HDIM + n]);
                h1reg = hn;
                u16 hi = f2bf(hn);
                __builtin_nontemporal_store(hn,
                    &out[(size_t)(u - 1) * BSZ * HDIM + b * HDIM + n]);
                store_h_16B(stg, tid, hi, f2bf(hn - bf2f(hi)),
                            h1hi + (size_t)sA0 * HSLOT, h1lo + (size_t)sA0 * HSLOT,
                            b * HDIM);
            }
        } else if (u + 1 < TSTEPS) {
            // taskA(u+1): hosts blocks 0-63 (idx=blk) and 128-255 (idx=blk-64)
            const int idx = (blk < 64) ? blk : (blk - 64);
            const int t = idx * 16 + wv;
            if (t < 2048)
                taskA(t, lane, stgw,
                      h0hi + (size_t)s0 * HSLOT, h0lo + (size_t)s0 * HSLOT,
                      Whthi, Whtlo, parts0);
        }
        grid_barrier(bar, ++nbar, fence);
    }

    // ---- final states: h0, h1, c0, c1 ----
    {
        const size_t F = (size_t)TSTEPS * BSZ * HDIM;
        if (blk < 64) {
            out[F +          blk * HDIM + tid] = h0reg;
            out[F + 131072 + blk * HDIM + tid] = c0reg;
        } else if (blk < 128) {
            const int b = blk - 64;
            out[F +  65536 + b * HDIM + tid] = h1reg;
            out[F + 196608 + b * HDIM + tid] = c1reg;
        }
    }
}

// =====================================================================
// prep kernels
// =====================================================================
__global__ __launch_bounds__(256) void transpose_split(
    const float* __restrict__ src, int N,
    u16* __restrict__ dsthi, u16* __restrict__ dstlo,
    int ldd, int noff, int koff)
{
    __shared__ float tile[32][33];
    const int n0 = blockIdx.x * 32, k0 = blockIdx.y * 32;
    const int tx = threadIdx.x & 31, ty = threadIdx.x >> 5;
#pragma unroll
    for (int i = 0; i < 4; ++i)
        tile[ty + i * 8][tx] = src[(size_t)(k0 + ty + i * 8) * N + n0 + tx];
    __syncthreads();
#pragma unroll
    for (int i = 0; i < 4; ++i) {
        float v = tile[tx][ty + i * 8];
        u16 hi = f2bf(v);
        u16 lo = f2bf(v - bf2f(hi));
        size_t idx = (size_t)(n0 + ty + i * 8 + noff) * ldd + k0 + koff + tx;
        dsthi[idx] = hi;
        dstlo[idx] = lo;
    }
}

__global__ void conv_split(const float* __restrict__ src,
                           u16* __restrict__ hi, u16* __restrict__ lo, int n4)
{
    int i = blockIdx.x * 256 + threadIdx.x;
    if (i < n4) {
        float4 v = ((const float4*)src)[i];
        ushort4 h, l;
        h.x = f2bf(v.x); l.x = f2bf(v.x - bf2f(h.x));
        h.y = f2bf(v.y); l.y = f2bf(v.y - bf2f(h.y));
        h.z = f2bf(v.z); l.z = f2bf(v.z - bf2f(h.z));
        h.w = f2bf(v.w); l.w = f2bf(v.w - bf2f(h.w));
        ((ushort4*)hi)[i] = h;
        ((ushort4*)lo)[i] = l;
    }
}

// =====================================================================
extern "C" void kernel_launch(void* const* d_in, const int* in_sizes, int n_in,
                              void* d_out, int out_size, void* d_ws, size_t ws_size,
                              hipStream_t stream)
{
    const float* x     = (const float*)d_in[0];
    const float* Wproj = (const float*)d_in[1];
    const float* Wx0   = (const float*)d_in[2];
    const float* Wh0   = (const float*)d_in[3];
    const float* b0    = (const float*)d_in[4];
    const float* Wx1   = (const float*)d_in[5];
    const float* Wh1   = (const float*)d_in[6];
    const float* b1    = (const float*)d_in[7];
    const float* lnc_g = (const float*)d_in[8];
    const float* lnc_b = (const float*)d_in[9];
    const float* lnh_g = (const float*)d_in[10];
    const float* lnh_b = (const float*)d_in[11];
    const float* lno_g = (const float*)d_in[12];
    const float* lno_b = (const float*)d_in[13];
    float* out = (float*)d_out;

    // ---- ws layout (~122 MB) ----
    char* base = (char*)d_ws;
    size_t o = 0;
    u16* x_hi  = (u16*)(base + o); o += (size_t)TSTEPS * BSZ * INDIM * 2;
    u16* x_lo  = (u16*)(base + o); o += (size_t)TSTEPS * BSZ * INDIM * 2;
    u16* Whthi = (u16*)(base + o); o += (size_t)G4 * HDIM * 2;
    u16* Whtlo = (u16*)(base + o); o += (size_t)G4 * HDIM * 2;
    u16* Wxthi = (u16*)(base + o); o += (size_t)NX * INDIM * 2;
    u16* Wxtlo = (u16*)(base + o); o += (size_t)NX * INDIM * 2;
    u16* W1thi = (u16*)(base + o); o += (size_t)G4 * 2048 * 2;
    u16* W1tlo = (u16*)(base + o); o += (size_t)G4 * 2048 * 2;
    float* xg     = (float*)(base + o); o += (size_t)2 * CROWS * NX * 4;
    float* parts0 = (float*)(base + o); o += (size_t)2 * BSZ * G4 * 4;
    float* parts1 = (float*)(base + o); o += (size_t)2 * BSZ * G4 * 4;
    u16* h0hi = (u16*)(base + o); o += (size_t)HRING * HSLOT * 2;
    u16* h0lo = (u16*)(base + o); o += (size_t)HRING * HSLOT * 2;
    u16* h1hi = (u16*)(base + o); o += (size_t)HRING * HSLOT * 2;
    u16* h1lo = (u16*)(base + o); o += (size_t)HRING * HSLOT * 2;
    int* bar  = (int*)(base + o); o += 40960;
    if (ws_size < o) return;   // fail loudly (poisoned out) if ws too small

    // ---- prep ----
    conv_split<<<dim3(8192), 256, 0, stream>>>(x, x_hi, x_lo, 2097152);
    transpose_split<<<dim3(128, 32), 256, 0, stream>>>(Wh0, G4, Whthi, Whtlo, HDIM, 0, 0);
    transpose_split<<<dim3(128, 8),  256, 0, stream>>>(Wx0,   G4,   Wxthi, Wxtlo, INDIM, 0,    0);
    transpose_split<<<dim3(32, 8),   256, 0, stream>>>(Wproj, HDIM, Wxthi, Wxtlo, INDIM, 4096, 0);
    transpose_split<<<dim3(128, 32), 256, 0, stream>>>(Wx1, G4, W1thi, W1tlo, 2048, 0, 0);
    transpose_split<<<dim3(128, 32), 256, 0, stream>>>(Wh1, G4, W1thi, W1tlo, 2048, 0, 1024);
    // zero: parts0 (h0(-1)=0), h rings (first reads must be 0), barrier block
    hipMemsetAsync(parts0, 0, (size_t)2 * BSZ * G4 * 4, stream);
    hipMemsetAsync(h0hi, 0, (size_t)4 * HRING * HSLOT * 2, stream);  // contiguous
    hipMemsetAsync(bar, 0, 40960, stream);

    // ---- the whole recurrence: one persistent kernel ----
    persistent<<<dim3(NBLK), dim3(NTHR), LDS_BYTES, stream>>>(
        x_hi, x_lo, Whthi, Whtlo, Wxthi, Wxtlo, W1thi, W1tlo, b0, b1,
        lnc_g, lnc_b, lnh_g, lnh_b, lno_g, lno_b,
        xg, parts0, parts1,
        h0hi, h0lo, h1hi, h1lo, out, bar);
}

// Round 16
// 24318.513 us; speedup vs baseline: 1.5793x; 1.5793x over previous
//
#include <hip/hip_runtime.h>
#include <math.h>

// Problem dims
#define TSTEPS 512
#define BSZ    64
#define INDIM  256
#define HDIM   1024
#define G4     4096
#define NX     5120   // xg cols: 4096 gate + 1024 proj
#define LN_EPS 1e-5f

#define NBLK   256
#define NTHR   1024
#define CHUNK  8
#define CROWS  (CHUNK * BSZ)
#define NCHUNK (TSTEPS / CHUNK)
#define HRING  16            // h ring slots; acquire fence every 16 steps
#define HSLOT  65536         // u16 per slot (64 x 1024)

// LDS: W1 strip [16 cols][2054] hi then lo (stride == 3 mod 32 dwords: conflict-free)
#define LDS_LDK    2054
#define LDS_LO_OFF (16 * LDS_LDK)
#define LDS_W_BYTES (2 * 16 * LDS_LDK * 2)          // 131,456
#define LDS_STG_OFF LDS_W_BYTES                     // u16 stg_h[2048] = 4 KB
#define LDS_RED_OFF (LDS_W_BYTES + 4096)            // float red[16] (+pad 256B)
#define LDS_GST_OFF (LDS_RED_OFF + 256)             // float stg_g[16][256] = 16 KB
#define LDS_BYTES   (LDS_GST_OFF + 16384)           // 152,192 < 160 KB

typedef short          s8v __attribute__((ext_vector_type(8)));
typedef float          f4v __attribute__((ext_vector_type(4)));
typedef unsigned short u16;

#define MFMA __builtin_amdgcn_mfma_f32_16x16x32_bf16

__device__ __forceinline__ u16 f2bf(float f) {
    unsigned u = __float_as_uint(f);
    u += 0x7FFFu + ((u >> 16) & 1u);
    return (u16)(u >> 16);
}
__device__ __forceinline__ float bf2f(u16 h) {
    return __uint_as_float(((unsigned)h) << 16);
}
__device__ __forceinline__ float sigm(float x) { return 1.f / (1.f + expf(-x)); }

// ---- sc1 (L2-bypass, always-fresh) accessors for read-once mutable data ----
__device__ __forceinline__ float aldf(const float* p) {
    unsigned v = __hip_atomic_load((unsigned*)p, __ATOMIC_RELAXED,
                                   __HIP_MEMORY_SCOPE_AGENT);
    return __uint_as_float(v);
}
// 16B sc1 stores (write-through; drained by barrier's vmcnt(0))
__device__ __forceinline__ void ast16B(u16* p, s8v v) {
    asm volatile("global_store_dwordx4 %0, %1, off sc1"
                 :: "v"(p), "v"(v) : "memory");
}
__device__ __forceinline__ void ast16Bf(float* p, f4v v) {
    asm volatile("global_store_dwordx4 %0, %1, off sc1"
                 :: "v"(p), "v"(v) : "memory");
}

// ---- GEMM C-write: per-wave LDS stage -> one contiguous 16B/lane sc1 store.
__device__ __forceinline__ void store_c_16B(float* stgw, int lane, f4v acc,
                                            float* dst, int ld)
{
    const int row = lane & 15, kg = lane >> 4;
#pragma unroll
    for (int r = 0; r < 4; ++r)
        stgw[(kg * 4 + r) * 16 + row] = acc[r];
    f4v v = *(f4v*)(stgw + lane * 4);
    ast16Bf(dst + (lane >> 2) * ld + (lane & 3) * 4, v);
}

// ---------------- tree grid barrier ---------------------------------------
// Tree arrivals (16 groups x 16, 2KB-strided lines), root closer broadcasts
// go words, busy-spin relaxed load polls. Acquire fence every 16th step only
// (ring-16 staleness window spans exactly one fence).
#define GSTRIDE 512
__device__ __forceinline__ void grid_barrier(int* bar, int nbar, bool fence)
{
    asm volatile("s_waitcnt vmcnt(0)" ::: "memory");
    __syncthreads();
    if (threadIdx.x == 0) {
        const int g = blockIdx.x & 15;
        int* gctr = bar + g * GSTRIDE;
        int* ggo  = gctr + 32;
        int* root = bar + 16 * GSTRIDE;
        int v = __hip_atomic_fetch_add(gctr, 1, __ATOMIC_RELAXED,
                                       __HIP_MEMORY_SCOPE_AGENT);
        if (v == nbar * 16 - 1) {
            int rv = __hip_atomic_fetch_add(root, 1, __ATOMIC_RELAXED,
                                            __HIP_MEMORY_SCOPE_AGENT);
            if (rv == nbar * 16 - 1) {
#pragma unroll
                for (int g2 = 0; g2 < 16; ++g2)
                    __hip_atomic_store(bar + g2 * GSTRIDE + 32, nbar,
                                       __ATOMIC_RELAXED, __HIP_MEMORY_SCOPE_AGENT);
            }
        }
        while (__hip_atomic_load(ggo, __ATOMIC_RELAXED,
                                 __HIP_MEMORY_SCOPE_AGENT) < nbar) {}
        if (fence)
            __builtin_amdgcn_fence(__ATOMIC_ACQUIRE, "agent");  // inv L1/L2
        asm volatile("" ::: "memory");
    }
    __syncthreads();
}

// ---------------- taskA: gates0 h-part, K=1024 merged ---------------------
// Block blk owns col-tile ct=blk (cols blk*16..+16); rt in 0..3 per wave.
__device__ __forceinline__ void taskA(int blk, int rt, int lane, float* stgw,
    const u16* __restrict__ h0hi_s, const u16* __restrict__ h0lo_s,
    const u16* __restrict__ Whthi, const u16* __restrict__ Whtlo,
    float* __restrict__ parts0)
{
    const int row = lane & 15, kg = lane >> 4;
    const int m = rt * 16 + row;
    const u16* wh = Whthi + (size_t)(blk * 16 + row) * HDIM + kg * 8;
    const u16* wl = Whtlo + (size_t)(blk * 16 + row) * HDIM + kg * 8;
    const u16* ah = h0hi_s + (size_t)m * HDIM + kg * 8;
    const u16* al = h0lo_s + (size_t)m * HDIM + kg * 8;
    f4v acc = {0.f, 0.f, 0.f, 0.f};
    s8v Ah = *(const s8v*)(ah);
    s8v Al = *(const s8v*)(al);
    s8v Bh = *(const s8v*)(wh);
    s8v Bl = *(const s8v*)(wl);
#pragma unroll
    for (int i = 0; i < 32; ++i) {
        s8v nAh, nAl, nBh, nBl;
        if (i + 1 < 32) {
            const int kn = (i + 1) * 32;
            nAh = *(const s8v*)(ah + kn);
            nAl = *(const s8v*)(al + kn);
            nBh = *(const s8v*)(wh + kn);
            nBl = *(const s8v*)(wl + kn);
        }
        acc = MFMA(Ah, Bh, acc, 0, 0, 0);
        acc = MFMA(Ah, Bl, acc, 0, 0, 0);
        acc = MFMA(Al, Bh, acc, 0, 0, 0);
        Ah = nAh; Al = nAl; Bh = nBh; Bl = nBl;
    }
    store_c_16B(stgw, lane, acc,
                parts0 + (size_t)(rt * 16) * G4 + blk * 16, G4);
}

// ---------------- taskX: xg chunk GEMM, one 16x16 tile, K=256 -------------
__device__ __forceinline__ void taskX(int task, int c, int lane, float* stgw,
    const u16* __restrict__ xhi, const u16* __restrict__ xlo,
    const u16* __restrict__ Wxthi, const u16* __restrict__ Wxtlo,
    float* __restrict__ xgbuf)
{
    const int mt = task & 31, ct = task >> 5;
    const int row = lane & 15, kg = lane >> 4;
    const int mr = mt * 16 + row;
    const u16* ah = xhi + ((size_t)c * CROWS + mr) * INDIM + kg * 8;
    const u16* al = xlo + ((size_t)c * CROWS + mr) * INDIM + kg * 8;
    const u16* wh = Wxthi + (size_t)(ct * 16 + row) * INDIM + kg * 8;
    const u16* wl = Wxtlo + (size_t)(ct * 16 + row) * INDIM + kg * 8;
    f4v acc = {0.f, 0.f, 0.f, 0.f};
    s8v Ah = *(const s8v*)(ah);
    s8v Al = *(const s8v*)(al);
    s8v Bh = *(const s8v*)(wh);
    s8v Bl = *(const s8v*)(wl);
#pragma unroll
    for (int i = 0; i < 8; ++i) {
        s8v nAh, nAl, nBh, nBl;
        if (i + 1 < 8) {
            const int kn = (i + 1) * 32;
            nAh = *(const s8v*)(ah + kn);
            nAl = *(const s8v*)(al + kn);
            nBh = *(const s8v*)(wh + kn);
            nBl = *(const s8v*)(wl + kn);
        }
        acc = MFMA(Ah, Bh, acc, 0, 0, 0);
        acc = MFMA(Ah, Bl, acc, 0, 0, 0);
        acc = MFMA(Al, Bh, acc, 0, 0, 0);
        Ah = nAh; Al = nAl; Bh = nBh; Bl = nBl;
    }
    store_c_16B(stgw, lane, acc,
                xgbuf + (size_t)(mt * 16) * NX + ct * 16, NX);
}

// ---------------- taskC: GEMM1 K=2048 merged; rt = wave 0..3 --------------
__device__ __forceinline__ void taskC(int blk, int rt, int lane, float* stgw,
    const u16* __restrict__ shW,
    const u16* __restrict__ h0hi_s, const u16* __restrict__ h0lo_s,
    const u16* __restrict__ h1hi_s, const u16* __restrict__ h1lo_s,
    float* __restrict__ parts1)
{
    const int row = lane & 15, kg = lane >> 4;
    const int m = rt * 16 + row;
    f4v acc = {0.f, 0.f, 0.f, 0.f};
#pragma unroll
    for (int hs = 0; hs < 2; ++hs) {
        const u16* ah0 = (hs ? h1hi_s : h0hi_s) + (size_t)m * HDIM + kg * 8;
        const u16* al0 = (hs ? h1lo_s : h0lo_s) + (size_t)m * HDIM + kg * 8;
        const u16* sh  = shW + row * LDS_LDK + hs * 1024 + kg * 8;
        const u16* sl  = shW + LDS_LO_OFF + row * LDS_LDK + hs * 1024 + kg * 8;
        s8v Ah = *(const s8v*)(ah0);
        s8v Al = *(const s8v*)(al0);
#pragma unroll
        for (int i = 0; i < 32; ++i) {
            s8v nAh, nAl;
            if (i + 1 < 32) {
                nAh = *(const s8v*)(ah0 + (i + 1) * 32);
                nAl = *(const s8v*)(al0 + (i + 1) * 32);
            }
            const int kloc = i * 32;
            s8v Bh = *(const s8v*)(sh + kloc);
            s8v Bl = *(const s8v*)(sl + kloc);
            acc = MFMA(Ah, Bh, acc, 0, 0, 0);
            acc = MFMA(Ah, Bl, acc, 0, 0, 0);
            acc = MFMA(Al, Bh, acc, 0, 0, 0);
            Ah = nAh; Al = nAl;
        }
    }
    store_c_16B(stgw, lane, acc,
                parts1 + (size_t)(rt * 16) * G4 + blk * 16, G4);
}

// ---------------- block reduction + LN helpers ----------------------------
__device__ __forceinline__ float2 blk_sum2(float s, float q, float* red, int tid)
{
#pragma unroll
    for (int off = 32; off; off >>= 1) {
        s += __shfl_down(s, off);
        q += __shfl_down(q, off);
    }
    if ((tid & 63) == 0) { red[(tid >> 6) * 2] = s; red[(tid >> 6) * 2 + 1] = q; }
    __syncthreads();
    float ts = 0.f, tq = 0.f;
#pragma unroll
    for (int i = 0; i < 16; ++i) { ts += red[2 * i]; tq += red[2 * i + 1]; }
    __syncthreads();
    return make_float2(ts, tq);
}

__device__ __forceinline__ float lnorm(float v, float2 sq, float g, float b)
{
    float mean = sq.x * (1.f / 1024.f);
    float var  = sq.y * (1.f / 1024.f) - mean * mean;
    return (v - mean) * rsqrtf(var + LN_EPS) * g + b;
}

// stage h (hi,lo per-thread u16) through LDS -> 16B sc1 stores
__device__ __forceinline__ void store_h_16B(u16* stg, int tid,
                                            u16 hi, u16 lo,
                                            u16* dhi, u16* dlo, int base)
{
    stg[tid] = hi;
    stg[1024 + tid] = lo;
    __syncthreads();
    if (tid < 256) {
        const u16* src = stg + (tid >> 7) * 1024 + (tid & 127) * 8;
        s8v v = *(const s8v*)src;
        u16* dst = ((tid >> 7) == 0 ? dhi : dlo) + base + (tid & 127) * 8;
        ast16B(dst, v);
    }
    __syncthreads();
}

// =====================================================================
__global__ __launch_bounds__(NTHR, 4) void persistent(
    const u16* __restrict__ xhi,  const u16* __restrict__ xlo,
    const u16* __restrict__ Whthi, const u16* __restrict__ Whtlo,
    const u16* __restrict__ Wxthi, const u16* __restrict__ Wxtlo,
    const u16* __restrict__ W1thi, const u16* __restrict__ W1tlo,
    const float* __restrict__ b0, const float* __restrict__ b1,
    const float* __restrict__ lncg, const float* __restrict__ lncb,
    const float* __restrict__ lnhg, const float* __restrict__ lnhb,
    const float* __restrict__ lnog, const float* __restrict__ lnob,
    float* __restrict__ xg,                        // [2][512][5120]  (sc1)
    float* __restrict__ parts0,                    // [64][4096]      (sc1)
    float* __restrict__ parts1,                    // [64][4096]      (sc1)
    u16* __restrict__ h0hi, u16* __restrict__ h0lo,// [HRING][64][1024]
    u16* __restrict__ h1hi, u16* __restrict__ h1lo,// [HRING][64][1024]
    float* __restrict__ out, int* bar)
{
    extern __shared__ char smem[];
    u16*   shW   = (u16*)smem;
    u16*   stg   = (u16*)(smem + LDS_STG_OFF);
    float* red   = (float*)(smem + LDS_RED_OFF);
    float* stg_g = (float*)(smem + LDS_GST_OFF);

    const int blk  = blockIdx.x;
    const int tid  = threadIdx.x;
    const int wv   = tid >> 6;
    const int lane = tid & 63;
    float* stgw = stg_g + wv * 256;
    int nbar = 0;

    // recurrent per-thread state:
    //   blocks 0..63: c0,h0 of batch row blk; blocks 64..127: c1,h1 of row blk-64
    float c0reg = 0.f, h0reg = 0.f, c1reg = 0.f, h1reg = 0.f;

    // ---- prologue: LDS W1 strip (cols blk*16..+16, K=2048) ----
    {
        const size_t gcol = (size_t)(blk * 16 + wv) * 2048;
        for (int j = lane * 8; j < 2048; j += 512) {
            *(s8v*)(shW + wv * LDS_LDK + j)              = *(const s8v*)(W1thi + gcol + j);
            *(s8v*)(shW + LDS_LO_OFF + wv * LDS_LDK + j) = *(const s8v*)(W1tlo + gcol + j);
        }
    }
    grid_barrier(bar, ++nbar, false);

    // ---- prologue: xg chunk 0 (all blocks; 10240 tasks / 4096 waves) ----
    {
        const int g = blk * 16 + wv;
        for (int task = g; task < 10240; task += 4096)
            taskX(task, 0, lane, stgw, xhi, xlo, Wxthi, Wxtlo, xg);
    }
    grid_barrier(bar, ++nbar, false);
    // parts0 zeroed host-side (h0(-1)=0); h rings zeroed host-side.

    for (int t = 0; t < TSTEPS; ++t) {
        const int s0  = t & (HRING - 1);            // h0(t) slot
        const int s0p = (t - 1) & (HRING - 1);      // h0(t-1) / h1(t-1) slot
        const bool fence = ((t & 15) == 15);

        // ================= phase 1: cells =================
        if (blk < 64) {
            // ---- cell0(t): row b = blk ----
            const int b = blk, n = tid;
            const float* XG = xg + (size_t)((t >> 3) & 1) * CROWS * NX
                                 + (size_t)((t & 7) * BSZ + b) * NX;
            const float* P0 = parts0 + (size_t)b * G4;
            float gi = aldf(&XG[n])        + aldf(&P0[n])        + b0[n];
            float gf = aldf(&XG[1024 + n]) + aldf(&P0[1024 + n]) + b0[1024 + n];
            float gg = aldf(&XG[2048 + n]) + aldf(&P0[2048 + n]) + b0[2048 + n];
            float go = aldf(&XG[3072 + n]) + aldf(&P0[3072 + n]) + b0[3072 + n];
            float xp = aldf(&XG[4096 + n]);
            float cv = sigm(gf) * c0reg + expf(gi) * tanhf(gg);
            float2 r = blk_sum2(cv, cv * cv, red, tid);
            float cl = lnorm(cv, r, lncg[n], lncb[n]);
            c0reg = cl;
            float hv = sigm(go) * tanhf(cl);
            r = blk_sum2(hv, hv * hv, red, tid);
            float hl = lnorm(hv, r, lnhg[n], lnhb[n]) + xp;
            r = blk_sum2(hl, hl * hl, red, tid);
            float hn = lnorm(hl, r, lnog[n], lnob[n]);
            h0reg = hn;
            u16 hi = f2bf(hn);
            store_h_16B(stg, tid, hi, f2bf(hn - bf2f(hi)),
                        h0hi + (size_t)s0 * HSLOT, h0lo + (size_t)s0 * HSLOT,
                        b * HDIM);
        } else if (blk < 128 && t > 0) {
            // ---- cell1(t-1): row b = blk-64 ----
            const int b = blk - 64, n = tid;
            const float* P0 = parts1 + (size_t)b * G4;
            float gi = aldf(&P0[n])        + b1[n];
            float gf = aldf(&P0[1024 + n]) + b1[1024 + n];
            float gg = aldf(&P0[2048 + n]) + b1[2048 + n];
            float go = aldf(&P0[3072 + n]) + b1[3072 + n];
            float cv = sigm(gf) * c1reg + expf(gi) * tanhf(gg);
            float2 r = blk_sum2(cv, cv * cv, red, tid);
            float cl = lnorm(cv, r, lncg[HDIM + n], lncb[HDIM + n]);
            c1reg = cl;
            float hv = sigm(go) * tanhf(cl);
            r = blk_sum2(hv, hv * hv, red, tid);
            // residual h0(t-1): cached ring read (L2-hot: filled fresh at t-1)
            float h0v = bf2f(h0hi[(size_t)s0p * HSLOT + b * HDIM + n])
                      + bf2f(h0lo[(size_t)s0p * HSLOT + b * HDIM + n]);
            float hl = lnorm(hv, r, lnhg[HDIM + n], lnhb[HDIM + n]) + h0v;
            r = blk_sum2(hl, hl * hl, red, tid);
            float hn = lnorm(hl, r, lnog[HDIM + n], lnob[HDIM + n]);
            h1reg = hn;
            u16 hi = f2bf(hn);
            __builtin_nontemporal_store(hn, &out[(size_t)(t - 1) * BSZ * HDIM + b * HDIM + n]);
            store_h_16B(stg, tid, hi, f2bf(hn - bf2f(hi)),
                        h1hi + (size_t)s0p * HSLOT, h1lo + (size_t)s0p * HSLOT,
                        b * HDIM);
        }
        grid_barrier(bar, ++nbar, false);

        // ================= phase 2: GEMMs (all blocks) ====================
        // wv 0-3: taskC(t)  [h0(t) slot s0, h1(t-1) slot s0p] -> parts1
        // wv 4-7: taskA(t+1)[h0(t) slot s0]                   -> parts0
        // wv 8-15: spread taskX for chunk (t>>3)+1 (1280 tasks/step)
        if (wv < 4) {
            taskC(blk, wv, lane, stgw, shW,
                  h0hi + (size_t)s0 * HSLOT,  h0lo + (size_t)s0 * HSLOT,
                  h1hi + (size_t)s0p * HSLOT, h1lo + (size_t)s0p * HSLOT,
                  parts1);
        } else if (wv < 8) {
            if (t + 1 < TSTEPS)
                taskA(blk, wv - 4, lane, stgw,
                      h0hi + (size_t)s0 * HSLOT, h0lo + (size_t)s0 * HSLOT,
                      Whthi, Whtlo, parts0);
        } else {
            const int c = (t >> 3) + 1;
            if (c < NCHUNK) {
                float* xgbuf = xg + (size_t)(c & 1) * CROWS * NX;
                const int widx = blk * 8 + (wv - 8);        // 0..2047
                if (widx < 1280)
                    taskX((t & 7) * 1280 + widx, c, lane, stgw,
                          xhi, xlo, Wxthi, Wxtlo, xgbuf);
            }
        }
        grid_barrier(bar, ++nbar, fence);
    }

    // ---- epilogue: cell1(511) ----
    if (blk >= 64 && blk < 128) {
        const int b = blk - 64, n = tid;
        const int tp = TSTEPS - 1;
        const int sp = tp & (HRING - 1);
        const float* P0 = parts1 + (size_t)b * G4;
        float gi = aldf(&P0[n])        + b1[n];
        float gf = aldf(&P0[1024 + n]) + b1[1024 + n];
        float gg = aldf(&P0[2048 + n]) + b1[2048 + n];
        float go = aldf(&P0[3072 + n]) + b1[3072 + n];
        float cv = sigm(gf) * c1reg + expf(gi) * tanhf(gg);
        float2 r = blk_sum2(cv, cv * cv, red, tid);
        float cl = lnorm(cv, r, lncg[HDIM + n], lncb[HDIM + n]);
        c1reg = cl;
        float hv = sigm(go) * tanhf(cl);
        r = blk_sum2(hv, hv * hv, red, tid);
        float h0v = bf2f(h0hi[(size_t)sp * HSLOT + b * HDIM + n])
                  + bf2f(h0lo[(size_t)sp * HSLOT + b * HDIM + n]);
        float hl = lnorm(hv, r, lnhg[HDIM + n], lnhb[HDIM + n]) + h0v;
        r = blk_sum2(hl, hl * hl, red, tid);
        float hn = lnorm(hl, r, lnog[HDIM + n], lnob[HDIM + n]);
        h1reg = hn;
        out[(size_t)tp * BSZ * HDIM + b * HDIM + n] = hn;
    }

    // ---- final states: h0, h1, c0, c1 ----
    {
        const size_t F = (size_t)TSTEPS * BSZ * HDIM;
        if (blk < 64) {
            out[F +          blk * HDIM + tid] = h0reg;
            out[F + 131072 + blk * HDIM + tid] = c0reg;
        } else if (blk < 128) {
            const int b = blk - 64;
            out[F +  65536 + b * HDIM + tid] = h1reg;
            out[F + 196608 + b * HDIM + tid] = c1reg;
        }
    }
}

// =====================================================================
// prep kernels
// =====================================================================
__global__ __launch_bounds__(256) void transpose_split(
    const float* __restrict__ src, int N,
    u16* __restrict__ dsthi, u16* __restrict__ dstlo,
    int ldd, int noff, int koff)
{
    __shared__ float tile[32][33];
    const int n0 = blockIdx.x * 32, k0 = blockIdx.y * 32;
    const int tx = threadIdx.x & 31, ty = threadIdx.x >> 5;
#pragma unroll
    for (int i = 0; i < 4; ++i)
        tile[ty + i * 8][tx] = src[(size_t)(k0 + ty + i * 8) * N + n0 + tx];
    __syncthreads();
#pragma unroll
    for (int i = 0; i < 4; ++i) {
        float v = tile[tx][ty + i * 8];
        u16 hi = f2bf(v);
        u16 lo = f2bf(v - bf2f(hi));
        size_t idx = (size_t)(n0 + ty + i * 8 + noff) * ldd + k0 + koff + tx;
        dsthi[idx] = hi;
        dstlo[idx] = lo;
    }
}

__global__ void conv_split(const float* __restrict__ src,
                           u16* __restrict__ hi, u16* __restrict__ lo, int n4)
{
    int i = blockIdx.x * 256 + threadIdx.x;
    if (i < n4) {
        float4 v = ((const float4*)src)[i];
        ushort4 h, l;
        h.x = f2bf(v.x); l.x = f2bf(v.x - bf2f(h.x));
        h.y = f2bf(v.y); l.y = f2bf(v.y - bf2f(h.y));
        h.z = f2bf(v.z); l.z = f2bf(v.z - bf2f(h.z));
        h.w = f2bf(v.w); l.w = f2bf(v.w - bf2f(h.w));
        ((ushort4*)hi)[i] = h;
        ((ushort4*)lo)[i] = l;
    }
}

// =====================================================================
extern "C" void kernel_launch(void* const* d_in, const int* in_sizes, int n_in,
                              void* d_out, int out_size, void* d_ws, size_t ws_size,
                              hipStream_t stream)
{
    const float* x     = (const float*)d_in[0];
    const float* Wproj = (const float*)d_in[1];
    const float* Wx0   = (const float*)d_in[2];
    const float* Wh0   = (const float*)d_in[3];
    const float* b0    = (const float*)d_in[4];
    const float* Wx1   = (const float*)d_in[5];
    const float* Wh1   = (const float*)d_in[6];
    const float* b1    = (const float*)d_in[7];
    const float* lnc_g = (const float*)d_in[8];
    const float* lnc_b = (const float*)d_in[9];
    const float* lnh_g = (const float*)d_in[10];
    const float* lnh_b = (const float*)d_in[11];
    const float* lno_g = (const float*)d_in[12];
    const float* lno_b = (const float*)d_in[13];
    float* out = (float*)d_out;

    // ---- ws layout (~118 MB) ----
    char* base = (char*)d_ws;
    size_t o = 0;
    u16* x_hi  = (u16*)(base + o); o += (size_t)TSTEPS * BSZ * INDIM * 2;
    u16* x_lo  = (u16*)(base + o); o += (size_t)TSTEPS * BSZ * INDIM * 2;
    u16* Whthi = (u16*)(base + o); o += (size_t)G4 * HDIM * 2;
    u16* Whtlo = (u16*)(base + o); o += (size_t)G4 * HDIM * 2;
    u16* Wxthi = (u16*)(base + o); o += (size_t)NX * INDIM * 2;
    u16* Wxtlo = (u16*)(base + o); o += (size_t)NX * INDIM * 2;
    u16* W1thi = (u16*)(base + o); o += (size_t)G4 * 2048 * 2;
    u16* W1tlo = (u16*)(base + o); o += (size_t)G4 * 2048 * 2;
    float* xg     = (float*)(base + o); o += (size_t)2 * CROWS * NX * 4;
    float* parts0 = (float*)(base + o); o += (size_t)BSZ * G4 * 4;
    float* parts1 = (float*)(base + o); o += (size_t)BSZ * G4 * 4;
    u16* h0hi = (u16*)(base + o); o += (size_t)HRING * HSLOT * 2;
    u16* h0lo = (u16*)(base + o); o += (size_t)HRING * HSLOT * 2;
    u16* h1hi = (u16*)(base + o); o += (size_t)HRING * HSLOT * 2;
    u16* h1lo = (u16*)(base + o); o += (size_t)HRING * HSLOT * 2;
    int* bar  = (int*)(base + o); o += 40960;
    if (ws_size < o) return;   // fail loudly (poisoned out) if ws too small

    // ---- prep ----
    conv_split<<<dim3(8192), 256, 0, stream>>>(x, x_hi, x_lo, 2097152);
    transpose_split<<<dim3(128, 32), 256, 0, stream>>>(Wh0, G4, Whthi, Whtlo, HDIM, 0, 0);
    transpose_split<<<dim3(128, 8),  256, 0, stream>>>(Wx0,   G4,   Wxthi, Wxtlo, INDIM, 0,    0);
    transpose_split<<<dim3(32, 8),   256, 0, stream>>>(Wproj, HDIM, Wxthi, Wxtlo, INDIM, 4096, 0);
    transpose_split<<<dim3(128, 32), 256, 0, stream>>>(Wx1, G4, W1thi, W1tlo, 2048, 0, 0);
    transpose_split<<<dim3(128, 32), 256, 0, stream>>>(Wh1, G4, W1thi, W1tlo, 2048, 0, 1024);
    // zero: parts0 (h0(-1)=0), h rings (first reads must be 0), barrier block
    hipMemsetAsync(parts0, 0, (size_t)BSZ * G4 * 4, stream);
    hipMemsetAsync(h0hi, 0, (size_t)4 * HRING * HSLOT * 2, stream);  // contiguous
    hipMemsetAsync(bar, 0, 40960, stream);

    // ---- the whole recurrence: one persistent kernel ----
    persistent<<<dim3(NBLK), dim3(NTHR), LDS_BYTES, stream>>>(
        x_hi, x_lo, Whthi, Whtlo, Wxthi, Wxtlo, W1thi, W1tlo, b0, b1,
        lnc_g, lnc_b, lnh_g, lnh_b, lno_g, lno_b,
        xg, parts0, parts1,
        h0hi, h0lo, h1hi, h1lo, out, bar);
}

// Round 17
// 24307.610 us; speedup vs baseline: 1.5800x; 1.0004x over previous
//
#include <hip/hip_runtime.h>
#include <math.h>

// Problem dims
#define TSTEPS 512
#define BSZ    64
#define INDIM  256
#define HDIM   1024
#define G4     4096
#define NX     5120   // xg cols: 4096 gate + 1024 proj
#define LN_EPS 1e-5f

#define NBLK   256
#define NTHR   1024
#define CHUNK  8
#define CROWS  (CHUNK * BSZ)
#define NCHUNK (TSTEPS / CHUNK)
#define HRING  16            // h ring slots
#define HSLOT  65536         // u16 per slot (64 x 1024)

// LDS: W1 strip [16 cols][2054] hi then lo (stride == 3 mod 32 dwords: conflict-free)
#define LDS_LDK    2054
#define LDS_LO_OFF (16 * LDS_LDK)
#define LDS_W_BYTES (2 * 16 * LDS_LDK * 2)          // 131,456
#define LDS_STG_OFF LDS_W_BYTES                     // u16 stg_h[2048] = 4 KB
#define LDS_RED_OFF (LDS_W_BYTES + 4096)            // float red[16] (+pad 256B)
#define LDS_GST_OFF (LDS_RED_OFF + 256)             // float stg_g[16][256] = 16 KB
#define LDS_BYTES   (LDS_GST_OFF + 16384)           // 152,192 < 160 KB

typedef short          s8v __attribute__((ext_vector_type(8)));
typedef float          f4v __attribute__((ext_vector_type(4)));
typedef unsigned short u16;

#define MFMA __builtin_amdgcn_mfma_f32_16x16x32_bf16

__device__ __forceinline__ u16 f2bf(float f) {
    unsigned u = __float_as_uint(f);
    u += 0x7FFFu + ((u >> 16) & 1u);
    return (u16)(u >> 16);
}
__device__ __forceinline__ float bf2f(u16 h) {
    return __uint_as_float(((unsigned)h) << 16);
}
__device__ __forceinline__ float sigm(float x) { return 1.f / (1.f + expf(-x)); }

// ---- sc1 (L2-bypass, always-fresh) accessors for read-once mutable data ----
__device__ __forceinline__ float aldf(const float* p) {
    unsigned v = __hip_atomic_load((unsigned*)p, __ATOMIC_RELAXED,
                                   __HIP_MEMORY_SCOPE_AGENT);
    return __uint_as_float(v);
}
// 16B sc1 stores (write-through; drained by barrier's vmcnt(0))
__device__ __forceinline__ void ast16B(u16* p, s8v v) {
    asm volatile("global_store_dwordx4 %0, %1, off sc1"
                 :: "v"(p), "v"(v) : "memory");
}
__device__ __forceinline__ void ast16Bf(float* p, f4v v) {
    asm volatile("global_store_dwordx4 %0, %1, off sc1"
                 :: "v"(p), "v"(v) : "memory");
}

// ---- GEMM C-write: per-wave LDS stage -> one contiguous 16B/lane sc1 store.
__device__ __forceinline__ void store_c_16B(float* stgw, int lane, f4v acc,
                                            float* dst, int ld)
{
    const int row = lane & 15, kg = lane >> 4;
#pragma unroll
    for (int r = 0; r < 4; ++r)
        stgw[(kg * 4 + r) * 16 + row] = acc[r];
    f4v v = *(f4v*)(stgw + lane * 4);
    ast16Bf(dst + (lane >> 2) * ld + (lane & 3) * 4, v);
}

// ---------------- tree grid barrier ---------------------------------------
// Tree arrivals (16 groups x 16, 2KB-strided lines), root closer broadcasts
// go words, busy-spin relaxed load polls. Acquire fence every 8th step:
// R17 audit — ring-16 + fence-16 left a staleness window for t==15 mod 16
// (no fence between last old-gen cached read at t-15 ph1 and first new-gen
// read at t ph2); fence-8 provably covers every 15-step window.
#define GSTRIDE 512
__device__ __forceinline__ void grid_barrier(int* bar, int nbar, bool fence)
{
    asm volatile("s_waitcnt vmcnt(0)" ::: "memory");
    __syncthreads();
    if (threadIdx.x == 0) {
        const int g = blockIdx.x & 15;
        int* gctr = bar + g * GSTRIDE;
        int* ggo  = gctr + 32;
        int* root = bar + 16 * GSTRIDE;
        int v = __hip_atomic_fetch_add(gctr, 1, __ATOMIC_RELAXED,
                                       __HIP_MEMORY_SCOPE_AGENT);
        if (v == nbar * 16 - 1) {
            int rv = __hip_atomic_fetch_add(root, 1, __ATOMIC_RELAXED,
                                            __HIP_MEMORY_SCOPE_AGENT);
            if (rv == nbar * 16 - 1) {
#pragma unroll
                for (int g2 = 0; g2 < 16; ++g2)
                    __hip_atomic_store(bar + g2 * GSTRIDE + 32, nbar,
                                       __ATOMIC_RELAXED, __HIP_MEMORY_SCOPE_AGENT);
            }
        }
        while (__hip_atomic_load(ggo, __ATOMIC_RELAXED,
                                 __HIP_MEMORY_SCOPE_AGENT) < nbar) {}
        if (fence)
            __builtin_amdgcn_fence(__ATOMIC_ACQUIRE, "agent");  // inv L1/L2
        asm volatile("" ::: "memory");
    }
    __syncthreads();
}

// ---------------- taskA: gates0 h-part, K=1024 merged ---------------------
// Block blk owns col-tile ct=blk (cols blk*16..+16); rt in 0..3 per wave.
__device__ __forceinline__ void taskA(int blk, int rt, int lane, float* stgw,
    const u16* __restrict__ h0hi_s, const u16* __restrict__ h0lo_s,
    const u16* __restrict__ Whthi, const u16* __restrict__ Whtlo,
    float* __restrict__ parts0)
{
    const int row = lane & 15, kg = lane >> 4;
    const int m = rt * 16 + row;
    const u16* wh = Whthi + (size_t)(blk * 16 + row) * HDIM + kg * 8;
    const u16* wl = Whtlo + (size_t)(blk * 16 + row) * HDIM + kg * 8;
    const u16* ah = h0hi_s + (size_t)m * HDIM + kg * 8;
    const u16* al = h0lo_s + (size_t)m * HDIM + kg * 8;
    f4v acc = {0.f, 0.f, 0.f, 0.f};
    s8v Ah = *(const s8v*)(ah);
    s8v Al = *(const s8v*)(al);
    s8v Bh = *(const s8v*)(wh);
    s8v Bl = *(const s8v*)(wl);
#pragma unroll
    for (int i = 0; i < 32; ++i) {
        s8v nAh, nAl, nBh, nBl;
        if (i + 1 < 32) {
            const int kn = (i + 1) * 32;
            nAh = *(const s8v*)(ah + kn);
            nAl = *(const s8v*)(al + kn);
            nBh = *(const s8v*)(wh + kn);
            nBl = *(const s8v*)(wl + kn);
        }
        acc = MFMA(Ah, Bh, acc, 0, 0, 0);
        acc = MFMA(Ah, Bl, acc, 0, 0, 0);
        acc = MFMA(Al, Bh, acc, 0, 0, 0);
        Ah = nAh; Al = nAl; Bh = nBh; Bl = nBl;
    }
    store_c_16B(stgw, lane, acc,
                parts0 + (size_t)(rt * 16) * G4 + blk * 16, G4);
}

// ---------------- taskX: xg chunk GEMM, one 16x16 tile, K=256 -------------
__device__ __forceinline__ void taskX(int task, int c, int lane, float* stgw,
    const u16* __restrict__ xhi, const u16* __restrict__ xlo,
    const u16* __restrict__ Wxthi, const u16* __restrict__ Wxtlo,
    float* __restrict__ xgbuf)
{
    const int mt = task & 31, ct = task >> 5;
    const int row = lane & 15, kg = lane >> 4;
    const int mr = mt * 16 + row;
    const u16* ah = xhi + ((size_t)c * CROWS + mr) * INDIM + kg * 8;
    const u16* al = xlo + ((size_t)c * CROWS + mr) * INDIM + kg * 8;
    const u16* wh = Wxthi + (size_t)(ct * 16 + row) * INDIM + kg * 8;
    const u16* wl = Wxtlo + (size_t)(ct * 16 + row) * INDIM + kg * 8;
    f4v acc = {0.f, 0.f, 0.f, 0.f};
    s8v Ah = *(const s8v*)(ah);
    s8v Al = *(const s8v*)(al);
    s8v Bh = *(const s8v*)(wh);
    s8v Bl = *(const s8v*)(wl);
#pragma unroll
    for (int i = 0; i < 8; ++i) {
        s8v nAh, nAl, nBh, nBl;
        if (i + 1 < 8) {
            const int kn = (i + 1) * 32;
            nAh = *(const s8v*)(ah + kn);
            nAl = *(const s8v*)(al + kn);
            nBh = *(const s8v*)(wh + kn);
            nBl = *(const s8v*)(wl + kn);
        }
        acc = MFMA(Ah, Bh, acc, 0, 0, 0);
        acc = MFMA(Ah, Bl, acc, 0, 0, 0);
        acc = MFMA(Al, Bh, acc, 0, 0, 0);
        Ah = nAh; Al = nAl; Bh = nBh; Bl = nBl;
    }
    store_c_16B(stgw, lane, acc,
                xgbuf + (size_t)(mt * 16) * NX + ct * 16, NX);
}

// ---------------- taskC: GEMM1 K=2048 merged; rt = wave 0..3 --------------
// R17: depth-3 software prefetch on the global A streams (64-iteration
// dependent chain is the longest in the kernel; +16 VGPRs, cap 128).
__device__ __forceinline__ void taskC(int blk, int rt, int lane, float* stgw,
    const u16* __restrict__ shW,
    const u16* __restrict__ h0hi_s, const u16* __restrict__ h0lo_s,
    const u16* __restrict__ h1hi_s, const u16* __restrict__ h1lo_s,
    float* __restrict__ parts1)
{
    const int row = lane & 15, kg = lane >> 4;
    const int m = rt * 16 + row;
    f4v acc = {0.f, 0.f, 0.f, 0.f};
#pragma unroll
    for (int hs = 0; hs < 2; ++hs) {
        const u16* ah0 = (hs ? h1hi_s : h0hi_s) + (size_t)m * HDIM + kg * 8;
        const u16* al0 = (hs ? h1lo_s : h0lo_s) + (size_t)m * HDIM + kg * 8;
        const u16* sh  = shW + row * LDS_LDK + hs * 1024 + kg * 8;
        const u16* sl  = shW + LDS_LO_OFF + row * LDS_LDK + hs * 1024 + kg * 8;
        s8v A0h = *(const s8v*)(ah0);
        s8v A0l = *(const s8v*)(al0);
        s8v A1h = *(const s8v*)(ah0 + 32);
        s8v A1l = *(const s8v*)(al0 + 32);
#pragma unroll
        for (int i = 0; i < 32; ++i) {
            s8v nAh, nAl;
            if (i + 2 < 32) {
                nAh = *(const s8v*)(ah0 + (i + 2) * 32);
                nAl = *(const s8v*)(al0 + (i + 2) * 32);
            }
            const int kloc = i * 32;
            s8v Bh = *(const s8v*)(sh + kloc);
            s8v Bl = *(const s8v*)(sl + kloc);
            acc = MFMA(A0h, Bh, acc, 0, 0, 0);
            acc = MFMA(A0h, Bl, acc, 0, 0, 0);
            acc = MFMA(A0l, Bh, acc, 0, 0, 0);
            A0h = A1h; A0l = A1l;
            A1h = nAh; A1l = nAl;
        }
    }
    store_c_16B(stgw, lane, acc,
                parts1 + (size_t)(rt * 16) * G4 + blk * 16, G4);
}

// ---------------- block reduction + LN helpers ----------------------------
__device__ __forceinline__ float2 blk_sum2(float s, float q, float* red, int tid)
{
#pragma unroll
    for (int off = 32; off; off >>= 1) {
        s += __shfl_down(s, off);
        q += __shfl_down(q, off);
    }
    if ((tid & 63) == 0) { red[(tid >> 6) * 2] = s; red[(tid >> 6) * 2 + 1] = q; }
    __syncthreads();
    float ts = 0.f, tq = 0.f;
#pragma unroll
    for (int i = 0; i < 16; ++i) { ts += red[2 * i]; tq += red[2 * i + 1]; }
    __syncthreads();
    return make_float2(ts, tq);
}

__device__ __forceinline__ float lnorm(float v, float2 sq, float g, float b)
{
    float mean = sq.x * (1.f / 1024.f);
    float var  = sq.y * (1.f / 1024.f) - mean * mean;
    return (v - mean) * rsqrtf(var + LN_EPS) * g + b;
}

// stage h (hi,lo per-thread u16) through LDS -> 16B sc1 stores
__device__ __forceinline__ void store_h_16B(u16* stg, int tid,
                                            u16 hi, u16 lo,
                                            u16* dhi, u16* dlo, int base)
{
    stg[tid] = hi;
    stg[1024 + tid] = lo;
    __syncthreads();
    if (tid < 256) {
        const u16* src = stg + (tid >> 7) * 1024 + (tid & 127) * 8;
        s8v v = *(const s8v*)src;
        u16* dst = ((tid >> 7) == 0 ? dhi : dlo) + base + (tid & 127) * 8;
        ast16B(dst, v);
    }
    __syncthreads();
}

// =====================================================================
__global__ __launch_bounds__(NTHR, 4) void persistent(
    const u16* __restrict__ xhi,  const u16* __restrict__ xlo,
    const u16* __restrict__ Whthi, const u16* __restrict__ Whtlo,
    const u16* __restrict__ Wxthi, const u16* __restrict__ Wxtlo,
    const u16* __restrict__ W1thi, const u16* __restrict__ W1tlo,
    const float* __restrict__ b0, const float* __restrict__ b1,
    const float* __restrict__ lncg, const float* __restrict__ lncb,
    const float* __restrict__ lnhg, const float* __restrict__ lnhb,
    const float* __restrict__ lnog, const float* __restrict__ lnob,
    float* __restrict__ xg,                        // [2][512][5120]  (sc1)
    float* __restrict__ parts0,                    // [64][4096]      (sc1)
    float* __restrict__ parts1,                    // [64][4096]      (sc1)
    u16* __restrict__ h0hi, u16* __restrict__ h0lo,// [HRING][64][1024]
    u16* __restrict__ h1hi, u16* __restrict__ h1lo,// [HRING][64][1024]
    float* __restrict__ out, int* bar)
{
    extern __shared__ char smem[];
    u16*   shW   = (u16*)smem;
    u16*   stg   = (u16*)(smem + LDS_STG_OFF);
    float* red   = (float*)(smem + LDS_RED_OFF);
    float* stg_g = (float*)(smem + LDS_GST_OFF);

    const int blk  = blockIdx.x;
    const int tid  = threadIdx.x;
    const int wv   = tid >> 6;
    const int lane = tid & 63;
    float* stgw = stg_g + wv * 256;
    int nbar = 0;

    // recurrent per-thread state:
    //   blocks 0..63: c0,h0 of batch row blk; blocks 64..127: c1,h1 of row blk-64
    float c0reg = 0.f, h0reg = 0.f, c1reg = 0.f, h1reg = 0.f;

    // ---- prologue: LDS W1 strip (cols blk*16..+16, K=2048) ----
    {
        const size_t gcol = (size_t)(blk * 16 + wv) * 2048;
        for (int j = lane * 8; j < 2048; j += 512) {
            *(s8v*)(shW + wv * LDS_LDK + j)              = *(const s8v*)(W1thi + gcol + j);
            *(s8v*)(shW + LDS_LO_OFF + wv * LDS_LDK + j) = *(const s8v*)(W1tlo + gcol + j);
        }
    }
    grid_barrier(bar, ++nbar, false);

    // ---- prologue: xg chunk 0 (all blocks; 10240 tasks / 4096 waves) ----
    {
        const int g = blk * 16 + wv;
        for (int task = g; task < 10240; task += 4096)
            taskX(task, 0, lane, stgw, xhi, xlo, Wxthi, Wxtlo, xg);
    }
    grid_barrier(bar, ++nbar, false);
    // parts0 zeroed host-side (h0(-1)=0); h rings zeroed host-side.

    for (int t = 0; t < TSTEPS; ++t) {
        const int s0  = t & (HRING - 1);            // h0(t) slot
        const int s0p = (t - 1) & (HRING - 1);      // h0(t-1) / h1(t-1) slot
        const bool fence = ((t & 7) == 7);

        // ================= phase 1: cells =================
        if (blk < 64) {
            // ---- cell0(t): row b = blk ----
            const int b = blk, n = tid;
            const float* XG = xg + (size_t)((t >> 3) & 1) * CROWS * NX
                                 + (size_t)((t & 7) * BSZ + b) * NX;
            const float* P0 = parts0 + (size_t)b * G4;
            float gi = aldf(&XG[n])        + aldf(&P0[n])        + b0[n];
            float gf = aldf(&XG[1024 + n]) + aldf(&P0[1024 + n]) + b0[1024 + n];
            float gg = aldf(&XG[2048 + n]) + aldf(&P0[2048 + n]) + b0[2048 + n];
            float go = aldf(&XG[3072 + n]) + aldf(&P0[3072 + n]) + b0[3072 + n];
            float xp = aldf(&XG[4096 + n]);
            float cv = sigm(gf) * c0reg + expf(gi) * tanhf(gg);
            float2 r = blk_sum2(cv, cv * cv, red, tid);
            float cl = lnorm(cv, r, lncg[n], lncb[n]);
            c0reg = cl;
            float hv = sigm(go) * tanhf(cl);
            r = blk_sum2(hv, hv * hv, red, tid);
            float hl = lnorm(hv, r, lnhg[n], lnhb[n]) + xp;
            r = blk_sum2(hl, hl * hl, red, tid);
            float hn = lnorm(hl, r, lnog[n], lnob[n]);
            h0reg = hn;
            u16 hi = f2bf(hn);
            store_h_16B(stg, tid, hi, f2bf(hn - bf2f(hi)),
                        h0hi + (size_t)s0 * HSLOT, h0lo + (size_t)s0 * HSLOT,
                        b * HDIM);
        } else if (blk < 128 && t > 0) {
            // ---- cell1(t-1): row b = blk-64 ----
            const int b = blk - 64, n = tid;
            const float* P0 = parts1 + (size_t)b * G4;
            float gi = aldf(&P0[n])        + b1[n];
            float gf = aldf(&P0[1024 + n]) + b1[1024 + n];
            float gg = aldf(&P0[2048 + n]) + b1[2048 + n];
            float go = aldf(&P0[3072 + n]) + b1[3072 + n];
            float cv = sigm(gf) * c1reg + expf(gi) * tanhf(gg);
            float2 r = blk_sum2(cv, cv * cv, red, tid);
            float cl = lnorm(cv, r, lncg[HDIM + n], lncb[HDIM + n]);
            c1reg = cl;
            float hv = sigm(go) * tanhf(cl);
            r = blk_sum2(hv, hv * hv, red, tid);
            // residual h0(t-1): cached ring read (L2-hot: filled fresh at t-1)
            float h0v = bf2f(h0hi[(size_t)s0p * HSLOT + b * HDIM + n])
                      + bf2f(h0lo[(size_t)s0p * HSLOT + b * HDIM + n]);
            float hl = lnorm(hv, r, lnhg[HDIM + n], lnhb[HDIM + n]) + h0v;
            r = blk_sum2(hl, hl * hl, red, tid);
            float hn = lnorm(hl, r, lnog[HDIM + n], lnob[HDIM + n]);
            h1reg = hn;
            u16 hi = f2bf(hn);
            __builtin_nontemporal_store(hn, &out[(size_t)(t - 1) * BSZ * HDIM + b * HDIM + n]);
            store_h_16B(stg, tid, hi, f2bf(hn - bf2f(hi)),
                        h1hi + (size_t)s0p * HSLOT, h1lo + (size_t)s0p * HSLOT,
                        b * HDIM);
        }
        grid_barrier(bar, ++nbar, false);

        // ================= phase 2: GEMMs (all blocks) ====================
        // wv 0-3: taskC(t)  [h0(t) slot s0, h1(t-1) slot s0p] -> parts1
        // wv 4-7: taskA(t+1)[h0(t) slot s0]                   -> parts0
        // wv 8-15: spread taskX for chunk (t>>3)+1 (1280 tasks/step)
        if (wv < 4) {
            taskC(blk, wv, lane, stgw, shW,
                  h0hi + (size_t)s0 * HSLOT,  h0lo + (size_t)s0 * HSLOT,
                  h1hi + (size_t)s0p * HSLOT, h1lo + (size_t)s0p * HSLOT,
                  parts1);
        } else if (wv < 8) {
            if (t + 1 < TSTEPS)
                taskA(blk, wv - 4, lane, stgw,
                      h0hi + (size_t)s0 * HSLOT, h0lo + (size_t)s0 * HSLOT,
                      Whthi, Whtlo, parts0);
        } else {
            const int c = (t >> 3) + 1;
            if (c < NCHUNK) {
                float* xgbuf = xg + (size_t)(c & 1) * CROWS * NX;
                const int widx = blk * 8 + (wv - 8);        // 0..2047
                if (widx < 1280)
                    taskX((t & 7) * 1280 + widx, c, lane, stgw,
                          xhi, xlo, Wxthi, Wxtlo, xgbuf);
            }
        }
        grid_barrier(bar, ++nbar, fence);
    }

    // ---- epilogue: cell1(511) ----
    if (blk >= 64 && blk < 128) {
        const int b = blk - 64, n = tid;
        const int tp = TSTEPS - 1;
        const int sp = tp & (HRING - 1);
        const float* P0 = parts1 + (size_t)b * G4;
        float gi = aldf(&P0[n])        + b1[n];
        float gf = aldf(&P0[1024 + n]) + b1[1024 + n];
        float gg = aldf(&P0[2048 + n]) + b1[2048 + n];
        float go = aldf(&P0[3072 + n]) + b1[3072 + n];
        float cv = sigm(gf) * c1reg + expf(gi) * tanhf(gg);
        float2 r = blk_sum2(cv, cv * cv, red, tid);
        float cl = lnorm(cv, r, lncg[HDIM + n], lncb[HDIM + n]);
        c1reg = cl;
        float hv = sigm(go) * tanhf(cl);
        r = blk_sum2(hv, hv * hv, red, tid);
        float h0v = bf2f(h0hi[(size_t)sp * HSLOT + b * HDIM + n])
                  + bf2f(h0lo[(size_t)sp * HSLOT + b * HDIM + n]);
        float hl = lnorm(hv, r, lnhg[HDIM + n], lnhb[HDIM + n]) + h0v;
        r = blk_sum2(hl, hl * hl, red, tid);
        float hn = lnorm(hl, r, lnog[HDIM + n], lnob[HDIM + n]);
        h1reg = hn;
        out[(size_t)tp * BSZ * HDIM + b * HDIM + n] = hn;
    }

    // ---- final states: h0, h1, c0, c1 ----
    {
        const size_t F = (size_t)TSTEPS * BSZ * HDIM;
        if (blk < 64) {
            out[F +          blk * HDIM + tid] = h0reg;
            out[F + 131072 + blk * HDIM + tid] = c0reg;
        } else if (blk < 128) {
            const int b = blk - 64;
            out[F +  65536 + b * HDIM + tid] = h1reg;
            out[F + 196608 + b * HDIM + tid] = c1reg;
        }
    }
}

// =====================================================================
// prep kernels
// =====================================================================
__global__ __launch_bounds__(256) void transpose_split(
    const float* __restrict__ src, int N,
    u16* __restrict__ dsthi, u16* __restrict__ dstlo,
    int ldd, int noff, int koff)
{
    __shared__ float tile[32][33];
    const int n0 = blockIdx.x * 32, k0 = blockIdx.y * 32;
    const int tx = threadIdx.x & 31, ty = threadIdx.x >> 5;
#pragma unroll
    for (int i = 0; i < 4; ++i)
        tile[ty + i * 8][tx] = src[(size_t)(k0 + ty + i * 8) * N + n0 + tx];
    __syncthreads();
#pragma unroll
    for (int i = 0; i < 4; ++i) {
        float v = tile[tx][ty + i * 8];
        u16 hi = f2bf(v);
        u16 lo = f2bf(v - bf2f(hi));
        size_t idx = (size_t)(n0 + ty + i * 8 + noff) * ldd + k0 + koff + tx;
        dsthi[idx] = hi;
        dstlo[idx] = lo;
    }
}

__global__ void conv_split(const float* __restrict__ src,
                           u16* __restrict__ hi, u16* __restrict__ lo, int n4)
{
    int i = blockIdx.x * 256 + threadIdx.x;
    if (i < n4) {
        float4 v = ((const float4*)src)[i];
        ushort4 h, l;
        h.x = f2bf(v.x); l.x = f2bf(v.x - bf2f(h.x));
        h.y = f2bf(v.y); l.y = f2bf(v.y - bf2f(h.y));
        h.z = f2bf(v.z); l.z = f2bf(v.z - bf2f(h.z));
        h.w = f2bf(v.w); l.w = f2bf(v.w - bf2f(h.w));
        ((ushort4*)hi)[i] = h;
        ((ushort4*)lo)[i] = l;
    }
}

// =====================================================================
extern "C" void kernel_launch(void* const* d_in, const int* in_sizes, int n_in,
                              void* d_out, int out_size, void* d_ws, size_t ws_size,
                              hipStream_t stream)
{
    const float* x     = (const float*)d_in[0];
    const float* Wproj = (const float*)d_in[1];
    const float* Wx0   = (const float*)d_in[2];
    const float* Wh0   = (const float*)d_in[3];
    const float* b0    = (const float*)d_in[4];
    const float* Wx1   = (const float*)d_in[5];
    const float* Wh1   = (const float*)d_in[6];
    const float* b1    = (const float*)d_in[7];
    const float* lnc_g = (const float*)d_in[8];
    const float* lnc_b = (const float*)d_in[9];
    const float* lnh_g = (const float*)d_in[10];
    const float* lnh_b = (const float*)d_in[11];
    const float* lno_g = (const float*)d_in[12];
    const float* lno_b = (const float*)d_in[13];
    float* out = (float*)d_out;

    // ---- ws layout (~118 MB) ----
    char* base = (char*)d_ws;
    size_t o = 0;
    u16* x_hi  = (u16*)(base + o); o += (size_t)TSTEPS * BSZ * INDIM * 2;
    u16* x_lo  = (u16*)(base + o); o += (size_t)TSTEPS * BSZ * INDIM * 2;
    u16* Whthi = (u16*)(base + o); o += (size_t)G4 * HDIM * 2;
    u16* Whtlo = (u16*)(base + o); o += (size_t)G4 * HDIM * 2;
    u16* Wxthi = (u16*)(base + o); o += (size_t)NX * INDIM * 2;
    u16* Wxtlo = (u16*)(base + o); o += (size_t)NX * INDIM * 2;
    u16* W1thi = (u16*)(base + o); o += (size_t)G4 * 2048 * 2;
    u16* W1tlo = (u16*)(base + o); o += (size_t)G4 * 2048 * 2;
    float* xg     = (float*)(base + o); o += (size_t)2 * CROWS * NX * 4;
    float* parts0 = (float*)(base + o); o += (size_t)BSZ * G4 * 4;
    float* parts1 = (float*)(base + o); o += (size_t)BSZ * G4 * 4;
    u16* h0hi = (u16*)(base + o); o += (size_t)HRING * HSLOT * 2;
    u16* h0lo = (u16*)(base + o); o += (size_t)HRING * HSLOT * 2;
    u16* h1hi = (u16*)(base + o); o += (size_t)HRING * HSLOT * 2;
    u16* h1lo = (u16*)(base + o); o += (size_t)HRING * HSLOT * 2;
    int* bar  = (int*)(base + o); o += 40960;
    if (ws_size < o) return;   // fail loudly (poisoned out) if ws too small

    // ---- prep ----
    conv_split<<<dim3(8192), 256, 0, stream>>>(x, x_hi, x_lo, 2097152);
    transpose_split<<<dim3(128, 32), 256, 0, stream>>>(Wh0, G4, Whthi, Whtlo, HDIM, 0, 0);
    transpose_split<<<dim3(128, 8),  256, 0, stream>>>(Wx0,   G4,   Wxthi, Wxtlo, INDIM, 0,    0);
    transpose_split<<<dim3(32, 8),   256, 0, stream>>>(Wproj, HDIM, Wxthi, Wxtlo, INDIM, 4096, 0);
    transpose_split<<<dim3(128, 32), 256, 0, stream>>>(Wx1, G4, W1thi, W1tlo, 2048, 0, 0);
    transpose_split<<<dim3(128, 32), 256, 0, stream>>>(Wh1, G4, W1thi, W1tlo, 2048, 0, 1024);
    // zero: parts0 (h0(-1)=0), h rings (first reads must be 0), barrier block
    hipMemsetAsync(parts0, 0, (size_t)BSZ * G4 * 4, stream);
    hipMemsetAsync(h0hi, 0, (size_t)4 * HRING * HSLOT * 2, stream);  // contiguous
    hipMemsetAsync(bar, 0, 40960, stream);

    // ---- the whole recurrence: one persistent kernel ----
    persistent<<<dim3(NBLK), dim3(NTHR), LDS_BYTES, stream>>>(
        x_hi, x_lo, Whthi, Whtlo, Wxthi, Wxtlo, W1thi, W1tlo, b0, b1,
        lnc_g, lnc_b, lnh_g, lnh_b, lno_g, lno_b,
        xg, parts0, parts1,
        h0hi, h0lo, h1hi, h1lo, out, bar);
}